// Round 4
// baseline (136.085 us; speedup 1.0000x reference)
//
#include <hip/hip_runtime.h>

// Tensor-train per-token contraction (fp32):
//   y[t,p,q,o] = relu(bias[p,q,o] + sum_{i,j,k,r,s} a[p,i,r] b[q,j,r,s] c[o,k,s] x[t,i,j,k])
// x: [65536,512] (i*64+j*8+k), out: [65536,1024] (p*128+q*16+o).
//
// One persistent wave handles 4 tokens. Per token:
//   A: lane=(j,k) -> t1[p; r-pair]   64 pk_fma, 8x ds_write_b64   (T1 swizzled)
//   B: lane=(p,k) -> t2[q; s-pair]  128 pk_fma, 8x b64 rd + 8x b64 wr (T2 swizzled)
//   C: lane=(q,p) -> y[o]           128 pk_fma, 8x b64 rd
//   Y-transpose through LDS (4x b128 wr + 4x b128 rd, XOR-swizzled) so the
//   4 global stores are each a fully-coalesced contiguous 1KB.
// NO barriers/fences: each wave owns a private 4KB LDS slice; per-wave DS ops
// execute in order on the LDS pipe, and the compiler preserves may-alias DS
// ordering (runtime lane-dependent indices can't be proven disjoint).
// All coefficient indices are compile-time -> wave-uniform s_loads.
// LDS layouts (dword units, all bank-minimal):
//   T1 (p,r,j,k): p*128 + (j^(p&1))*16 + k*2 + r
//   T2 (q,s,p,k): q*128 + p*16 + (k^q)*2 + s
//   Y: writer lane lw=q*8+p, chunk mw -> lw*16 + ((mw ^ ((lw>>1)&3))<<2)
//      reader lane l, chunk m: lw=((l>>2)&7)*8+2m+(l>>5), mw=l&3, swz==m
//      (both sides uniform 8 dwords/bank = b128 minimum, conflict-free)

typedef float f32x2 __attribute__((ext_vector_type(2)));
typedef float f32x4 __attribute__((ext_vector_type(4)));

#define NTOK  (16 * 4096)
#define NBLK  4096
#define NWAVE (NBLK * 4)

static __device__ __forceinline__ f32x2 mk2(float a, float b) {
    f32x2 r; r.x = a; r.y = b; return r;
}

__global__ __launch_bounds__(256) void tt_kernel(
    const float* __restrict__ x,
    const float* __restrict__ a,    // [8][8][2]    p,i,r
    const float* __restrict__ b,    // [8][8][2][2] q,j,r,s
    const float* __restrict__ c,    // [16][8][2]   o,k,s
    const float* __restrict__ bias, // [8][8][16]   p,q,o
    float* __restrict__ out)
{
    __shared__ alignas(16) float lds[4][1024];
    const int l  = threadIdx.x & 63;
    const int w  = threadIdx.x >> 6;
    float* buf   = lds[w];
    const int g  = blockIdx.x * 4 + w;

    const int hi = l >> 3;   // A: j | B: p | C: q
    const int lo = l & 7;    // A: k | B: k | C: p

    // Hoisted bias for stage-C role (p=lo, q=hi): 16 floats.
    float bv[16];
    {
        const f32x4* bp = (const f32x4*)(bias + (lo * 8 + hi) * 16);
#pragma unroll
        for (int m = 0; m < 4; ++m) {
            f32x4 t = bp[m];
            bv[m*4+0] = t.x; bv[m*4+1] = t.y; bv[m*4+2] = t.z; bv[m*4+3] = t.w;
        }
    }

    // Preload x for first token: lane's column x[t*512 + i*64 + l].
    float xi[8];
    {
        const float* xp = x + (size_t)g * 512 + l;
#pragma unroll
        for (int i = 0; i < 8; ++i) xi[i] = xp[i * 64];
    }

    for (int t = g; t < NTOK; t += NWAVE) {
        // ---------- Stage A: lane=(j=hi, k=lo) ----------
#pragma unroll
        for (int p = 0; p < 8; ++p) {
            f32x2 acc = mk2(0.f, 0.f);
#pragma unroll
            for (int i = 0; i < 8; ++i) {
                f32x2 A2 = *(const f32x2*)(a + p * 16 + i * 2); // (r0,r1)
                acc = __builtin_elementwise_fma(A2, mk2(xi[i], xi[i]), acc);
            }
            *(f32x2*)(buf + p * 128 + ((hi ^ (p & 1)) << 4) + (lo << 1)) = acc;
        }

        // Prefetch next token's x (latency hidden under B+C).
        const int tn = t + NWAVE;
        float xn[8];
        if (tn < NTOK) {
            const float* xp = x + (size_t)tn * 512 + l;
#pragma unroll
            for (int i = 0; i < 8; ++i) xn[i] = xp[i * 64];
        }

        // ---------- Stage B: lane=(p=hi, k=lo) ----------
        f32x2 u2[8];  // (r0,r1) per j
#pragma unroll
        for (int j = 0; j < 8; ++j)
            u2[j] = *(const f32x2*)(buf + hi * 128 + ((j ^ (hi & 1)) << 4) + (lo << 1));

#pragma unroll
        for (int q = 0; q < 8; ++q) {
            f32x2 acc = mk2(0.f, 0.f);  // (s0,s1)
#pragma unroll
            for (int j = 0; j < 8; ++j) {
                f32x2 B0 = *(const f32x2*)(b + q * 32 + j * 4 + 0); // r=0,(s0,s1)
                f32x2 B1 = *(const f32x2*)(b + q * 32 + j * 4 + 2); // r=1,(s0,s1)
                acc = __builtin_elementwise_fma(B0, mk2(u2[j].x, u2[j].x), acc);
                acc = __builtin_elementwise_fma(B1, mk2(u2[j].y, u2[j].y), acc);
            }
            *(f32x2*)(buf + q * 128 + hi * 16 + ((lo ^ q) << 1)) = acc;
        }

        // ---------- Stage C: lane=(q=hi, p=lo) ----------
        f32x2 v2[8];  // (s0,s1) per k
#pragma unroll
        for (int kk = 0; kk < 8; ++kk)
            v2[kk] = *(const f32x2*)(buf + hi * 128 + lo * 16 + ((kk ^ hi) << 1));

        float y[16];
#pragma unroll
        for (int o = 0; o < 16; ++o) {
            f32x2 acc = mk2(0.f, 0.f);
#pragma unroll
            for (int kk = 0; kk < 8; ++kk) {
                f32x2 C2 = *(const f32x2*)(c + o * 16 + kk * 2); // (s0,s1)
                acc = __builtin_elementwise_fma(C2, v2[kk], acc);
            }
            float v = acc.x + acc.y + bv[o];
            y[o] = v > 0.f ? v : 0.f;
        }

        // ---------- Y-transpose through LDS, then coalesced stores ----------
        const int swz = (l >> 1) & 3;   // writer lane swizzle
#pragma unroll
        for (int m = 0; m < 4; ++m) {
            f32x4 yv; yv.x = y[m*4+0]; yv.y = y[m*4+1]; yv.z = y[m*4+2]; yv.w = y[m*4+3];
            *(f32x4*)(buf + l * 16 + ((m ^ swz) << 2)) = yv;
        }

        float* op = out + (size_t)t * 1024;
#pragma unroll
        for (int m = 0; m < 4; ++m) {
            const int lw = ((l >> 2) & 7) * 8 + 2 * m + (l >> 5);
            f32x4 v = *(const f32x4*)(buf + lw * 16 + (((l & 3) ^ m) << 2));
            *(f32x4*)(op + m * 256 + l * 4) = v;
        }

#pragma unroll
        for (int i = 0; i < 8; ++i) xi[i] = xn[i];
    }
}

extern "C" void kernel_launch(void* const* d_in, const int* in_sizes, int n_in,
                              void* d_out, int out_size, void* d_ws, size_t ws_size,
                              hipStream_t stream) {
    const float* x    = (const float*)d_in[0];
    const float* a    = (const float*)d_in[1];
    const float* b    = (const float*)d_in[2];
    const float* c    = (const float*)d_in[3];
    const float* bias = (const float*)d_in[4];
    float* out = (float*)d_out;

    tt_kernel<<<NBLK, 256, 0, stream>>>(x, a, b, c, bias, out);
}

// Round 5
// 90.746 us; speedup vs baseline: 1.4996x; 1.4996x over previous
//
#include <hip/hip_runtime.h>

// Tensor-train per-token contraction (fp32):
//   y[t,p,q,o] = relu(bias[p,q,o] + sum_{i,j,k,r,s} a[p,i,r] b[q,j,r,s] c[o,k,s] x[t,i,j,k])
// x: [65536,512] (i*64+j*8+k), out: [65536,1024] (p*128+q*16+o).
//
// One wave per token (16384 blocks x 4 waves). Lane roles:
//   A: lane=(j,k)=(hi,lo)  t1[p; r-pair]  64 pk_fma, 8x ds_write_b64
//   B: lane=(p,k)=(hi,lo)  t2[q; s-pair] 128 pk_fma, 8x b64 rd + 8x b64 wr
//   C: lane=(p,q)=(hi,lo)  y[o] in 4-chunks, 128 pk_fma, 8x b64 rd, 4x b128 wr
//   store: 4x b128 rd + 4 coalesced 1KB global stores
// No barriers: each wave owns lds[w]; per-wave DS ops execute in order and the
// compiler preserves may-alias DS ordering (verified correct in R4).
// LDS layouts (dword units), bank-audited (free or 2-way=free):
//   T1 (p,r,j,k): p*128 + j*16 + k*2 + r            (plain; A-wr free, B-rd 2-way)
//   T2 (q,s,p,k): q*128 + p*16 + ((k^q)<<1) + s     (B-wr free, C-rd 2-way)
//     addr tricks: base bits1-3 hold a 3-bit index -> base^(idx<<1) applies XOR
//   Y  (p,q,m):   p*128 + q*16 + ((m^((q>>1)&3))<<2) (wr free, rd free)
// Minimal live registers (~50) -> high occupancy; that's the R2/R4 post-mortem fix.

typedef float f32x2 __attribute__((ext_vector_type(2)));
typedef float f32x4 __attribute__((ext_vector_type(4)));

#define NTOK (16 * 4096)

static __device__ __forceinline__ f32x2 mk2(float a, float b) {
    f32x2 r; r.x = a; r.y = b; return r;
}

__global__ __launch_bounds__(256, 6) void tt_kernel(
    const float* __restrict__ x,
    const float* __restrict__ a,    // [8][8][2]    p,i,r
    const float* __restrict__ b,    // [8][8][2][2] q,j,r,s
    const float* __restrict__ c,    // [16][8][2]   o,k,s
    const float* __restrict__ bias, // [8][8][16]   p,q,o
    float* __restrict__ out)
{
    __shared__ alignas(16) float lds[4][1024];
    const int l = threadIdx.x & 63;
    const int w = threadIdx.x >> 6;
    float* buf = lds[w];
    const int t = blockIdx.x * 4 + w;

    const int hi = l >> 3;   // A: j | B: p | C: p
    const int lo = l & 7;    // A: k | B: k | C: q

    // ---------------- load x: lane holds x[i, j=hi, k=lo] ----------------
    const float* xp = x + (size_t)t * 512 + l;
    float xi[8];
#pragma unroll
    for (int i = 0; i < 8; ++i) xi[i] = xp[i * 64];

    // ---------------- Stage A: t1[p,r] = sum_i a[p,i,r] x[i,j,k] ----------
    // T1 write at p*128 + hi*16 + lo*2 (+r). Conflict-free.
    {
        float* wA = buf + hi * 16 + lo * 2;
#pragma unroll
        for (int p = 0; p < 8; ++p) {
            f32x2 acc = mk2(0.f, 0.f);
#pragma unroll
            for (int i = 0; i < 8; ++i) {
                f32x2 A2 = *(const f32x2*)(a + p * 16 + i * 2);   // (r0,r1)
                acc = __builtin_elementwise_fma(A2, mk2(xi[i], xi[i]), acc);
            }
            *(f32x2*)(wA + p * 128) = acc;
        }
    }

    // ---------------- Stage B: t2[q,s] = sum_{j,r} b[q,j,r,s] t1[p,r,j,k] --
    {
        const float* rB = buf + hi * 128 + lo * 2;   // + j*16 (2-way, free)
        f32x2 u2[8];
#pragma unroll
        for (int j = 0; j < 8; ++j)
            u2[j] = *(const f32x2*)(rB + j * 16);

        const int wBb = hi * 16 + lo * 2;            // bits1-3 = k
#pragma unroll
        for (int q = 0; q < 8; ++q) {
            f32x2 acc = mk2(0.f, 0.f);               // (s0,s1)
#pragma unroll
            for (int j = 0; j < 8; ++j) {
                f32x2 B0 = *(const f32x2*)(b + q * 32 + j * 4 + 0); // r=0
                f32x2 B1 = *(const f32x2*)(b + q * 32 + j * 4 + 2); // r=1
                acc = __builtin_elementwise_fma(B0, mk2(u2[j].x, u2[j].x), acc);
                acc = __builtin_elementwise_fma(B1, mk2(u2[j].y, u2[j].y), acc);
            }
            // T2[q][p=hi][slot=(k^q)] : addr = (wBb ^ (q<<1)) + q*128
            *(f32x2*)(buf + ((wBb ^ (q << 1)) + q * 128)) = acc;
        }
    }

    // ---------------- Stage C: lane=(p=hi, q=lo) --------------------------
    {
        // T2 read: q*128 + p*16 + ((k^q)<<1) with q=lo,p=hi:
        //   base = lo*128 + hi*16 + lo*2 (bits1-3 = q=lo), addr_k = base^(k<<1)
        const int rCb = lo * 128 + hi * 16 + lo * 2;
        f32x2 v2[8];
#pragma unroll
        for (int k = 0; k < 8; ++k)
            v2[k] = *(const f32x2*)(buf + (rCb ^ (k << 1)));

        const float* bb = bias + l * 16;             // (p*8+q)*16 = l*16
        float* wY = buf + hi * 128 + lo * 16;        // y chunk base (p,q)
        const int ysw = (lo >> 1) & 3;
#pragma unroll
        for (int m = 0; m < 4; ++m) {
            f32x4 bv4 = *(const f32x4*)(bb + m * 4);
            float yg[4];
#pragma unroll
            for (int oo = 0; oo < 4; ++oo) {
                const int o = m * 4 + oo;
                f32x2 acc = mk2(bv4[oo], 0.f);
#pragma unroll
                for (int k = 0; k < 8; ++k) {
                    f32x2 C2 = *(const f32x2*)(c + o * 16 + k * 2); // (s0,s1)
                    acc = __builtin_elementwise_fma(C2, v2[k], acc);
                }
                float v = acc.x + acc.y;
                yg[oo] = v > 0.f ? v : 0.f;
            }
            f32x4 yv; yv.x = yg[0]; yv.y = yg[1]; yv.z = yg[2]; yv.w = yg[3];
            *(f32x4*)(wY + ((m ^ ysw) << 2)) = yv;
        }
    }

    // ---------------- coalesced store: instr m covers out[t*1024+m*256+l*4]
    // physical Y addr: writer (p_w=2m+b5, q_w=(l>>2)&7, chunk m_w=l&3),
    //   slot = m_w ^ ((q_w>>1)&3) -> m-independent base + m*256.
    {
        const int b5 = l >> 5;
        const int base_r = b5 * 128 + ((l >> 2) & 7) * 16 +
                           (((l & 3) ^ ((l >> 3) & 3)) << 2);
        float* op = out + (size_t)t * 1024 + l * 4;
#pragma unroll
        for (int m = 0; m < 4; ++m) {
            f32x4 v = *(const f32x4*)(buf + base_r + m * 256);
            *(f32x4*)(op + m * 256) = v;
        }
    }
}

extern "C" void kernel_launch(void* const* d_in, const int* in_sizes, int n_in,
                              void* d_out, int out_size, void* d_ws, size_t ws_size,
                              hipStream_t stream) {
    const float* x    = (const float*)d_in[0];
    const float* a    = (const float*)d_in[1];
    const float* b    = (const float*)d_in[2];
    const float* c    = (const float*)d_in[3];
    const float* bias = (const float*)d_in[4];
    float* out = (float*)d_out;

    tt_kernel<<<NTOK / 4, 256, 0, stream>>>(x, a, b, c, bias, out);
}